// Round 13
// baseline (344.275 us; speedup 1.0000x reference)
//
#include <hip/hip_runtime.h>
#include <hip/hip_bf16.h>
#include <stdint.h>

#define HEADS 16
#define DHEAD 64
#define DIM   1024
#define SEQ   4096
#define BATCH 4
#define MROWS (BATCH * SEQ)   // 16384
#define NQKV  (3 * DIM)       // 3072

typedef short  s16x8 __attribute__((ext_vector_type(8)));
typedef short  s16x4 __attribute__((ext_vector_type(4)));
typedef float  f32x4 __attribute__((ext_vector_type(4)));
typedef unsigned short u16;

__device__ __forceinline__ u16 f2bf(float f) {
  union { float f; uint32_t u; } v; v.f = f;
  uint32_t r = v.u + 0x7fffu + ((v.u >> 16) & 1u);  // RNE
  return (u16)(r >> 16);
}
__device__ __forceinline__ float bf2f(u16 h) {
  union { uint32_t u; float f; } v; v.u = ((uint32_t)h) << 16;
  return v.f;
}

// async global->LDS, 16B per lane; LDS dest is wave-uniform base + lane*16
__device__ __forceinline__ void gload_lds16(const void* g, void* l) {
  __builtin_amdgcn_global_load_lds((__attribute__((address_space(1))) void*)(g),
                                   (__attribute__((address_space(3))) void*)(l),
                                   16, 0, 0);
}

// ---------------- merged prologue: cast + fold_qk + 2x transpose_cast ----------------
// blocks 0..255    : fold W_f into q/k blocks of W_qkv (transposed bf16 out)
// blocks 256..511  : transpose+cast Wqkv v-columns -> wqkvT v region
// blocks 512..767  : transpose+cast Wout -> woutT
// blocks 768..2815 : cast x fp32 -> bf16 (grid-stride)
__global__ __launch_bounds__(256) void prep(const float* __restrict__ x,
                                            const float* __restrict__ Wqkv,
                                            const float* __restrict__ Wf,
                                            const float* __restrict__ Wout,
                                            u16* __restrict__ xb,
                                            u16* __restrict__ wqkvT,
                                            u16* __restrict__ woutT) {
  __shared__ __align__(16) char lds_raw[32768];
  const int bid = blockIdx.x;
  const int tid = threadIdx.x;

  if (bid < 256) {
    // ---- fold_qk (R6-proven body) ----
    float* wc = (float*)lds_raw;              // 128*64 fp32 = 32 KB
    const int rh  = bid >> 3;                 // 0..31 = (reg,h)
    const int kc  = (bid & 7) << 7;           // k-chunk base (128 each)
    const int reg = rh >> 4, h = rh & 15;
    const int base = reg * DIM + h * DHEAD;
    const int j  = tid & 63;
    const int kg = tid >> 6;
    for (int i = tid; i < 128 * 16; i += 256) {
      const int r = i >> 4, c4 = (i & 15) << 2;
      *(float4*)&wc[r * 64 + c4] = *(const float4*)&Wqkv[(size_t)(kc + r) * NQKV + base + c4];
    }
    float v[64];
#pragma unroll
    for (int d = 0; d < 64; d++) v[d] = Wf[d * 64 + j];
    __syncthreads();
    u16* dst = wqkvT + (size_t)(base + j) * DIM + kc + kg * 32;
    for (int ki = 0; ki < 32; ki++) {
      const int k = kg * 32 + ki;
      float s = 0.f;
#pragma unroll
      for (int d = 0; d < 64; d++) s += wc[k * 64 + d] * v[d];
      dst[ki] = f2bf(s);
    }
  } else if (bid < 768) {
    // ---- transpose_cast (two instances) ----
    float (*t)[65] = (float(*)[65])lds_raw;   // 64*65 fp32 = 16.6 KB
    const float* src;
    int srcStride, colOff;
    u16* dst;
    int tile = bid & 255;
    if (bid < 512) { src = Wqkv; srcStride = NQKV; colOff = 2 * DIM;
                     dst = wqkvT + (size_t)2 * DIM * DIM; }
    else           { src = Wout; srcStride = DIM;  colOff = 0; dst = woutT; }
    const int ntiles = DIM >> 6;              // 16
    const int n0 = (tile % ntiles) * 64;
    const int k0 = (tile / ntiles) * 64;
    for (int i = tid; i < 4096; i += 256) {
      const int r = i >> 6, c = i & 63;
      t[r][c] = src[(size_t)(k0 + r) * srcStride + colOff + n0 + c];
    }
    __syncthreads();
    for (int i = tid; i < 4096; i += 256) {
      const int r = i & 63, c = i >> 6;
      dst[(size_t)(n0 + c) * DIM + k0 + r] = f2bf(t[r][c]);
    }
  } else {
    // ---- cast x fp32 -> bf16 ----
    const int n = MROWS * DIM;
    int i = ((bid - 768) * 256 + tid) * 4;
    const int stride = 2048 * 256 * 4;
    for (; i < n; i += stride) {
      float4 f = *(const float4*)(x + i);
      ushort4 o;
      o.x = f2bf(f.x); o.y = f2bf(f.y); o.z = f2bf(f.z); o.w = f2bf(f.w);
      *(ushort4*)(xb + i) = o;
    }
  }
}

// ---------------- 256x256 4-phase MFMA GEMM (R9/R12 proven) ----------------
// Each phase = one m-row (mlo/mhi) x all n = 32 MFMAs. Stage placement by
// region-phase rule; vmcnt(4) at PhB0/PhB1 drains exactly the 8 ops of the
// buffer read next phase. A via gload_lds with pre-swizzled source.
template <int EPI>
__global__ __launch_bounds__(512, 2) void gemm4p(const u16* __restrict__ A,
                                                 const u16* __restrict__ Bt,
                                                 void* __restrict__ Cout,
                                                 const float* __restrict__ bias,
                                                 int Nn, int K) {
  __shared__ __align__(16) u16 smem[2][2][2][128 * 64];  // [buf][A0/B1][half] = 128 KiB
  const int tilesN = Nn >> 8;
  const int cpx   = gridDim.x >> 3;
  const int xcd   = blockIdx.x & 7;
  const int local = blockIdx.x >> 3;
  const int bmPerX = cpx / tilesN;
  const int perG = 4 * tilesN;
  const int g = local / perG, rrm = local % perG;
  const int bm = xcd * bmPerX + g * 4 + rrm / tilesN;
  const int bn = rrm % tilesN;
  const int m0 = bm << 8, n0 = bn << 8;

  const int tid  = threadIdx.x;
  const int lane = tid & 63;
  const int w    = tid >> 6;
  const int wr = w >> 2, wcn = w & 3;
  const int lrow = lane & 15;
  const int hi   = lane >> 4;
  const int sx   = lrow & 7;

  const int srow  = tid >> 3;
  const int pslot = tid & 7;
  const int gk    = (pslot ^ (srow & 7)) << 3;
  const u16* aBase = A  + (size_t)m0 * K + gk;
  const u16* bBase = Bt + (size_t)n0 * K + gk;

#define STG(buf, op, half, kt, gb)                                             \
  { const u16* s0_ = (gb) + (size_t)((half) * 128 + srow) * K + (kt) * 64;     \
    char* d0_ = (char*)&smem[buf][op][half][0] + tid * 16;                     \
    gload_lds16(s0_, d0_);                                                     \
    gload_lds16(s0_ + (size_t)64 * K, d0_ + 8192); }

#define RDA(buf, dst, mbase)                                                   \
  _Pragma("unroll") for (int mi_ = 0; mi_ < 4; mi_++)                          \
  _Pragma("unroll") for (int kk_ = 0; kk_ < 2; kk_++) {                        \
    const int r_ = ((mbase) + mi_) * 16 + lrow;                                \
    dst[mi_][kk_] = *(const s16x8*)&smem[buf][0][wr]                           \
                        [r_ * 64 + ((kk_ * 4 + hi) ^ sx) * 8]; }

#define RDB(buf, dst, nbase)                                                   \
  _Pragma("unroll") for (int nj_ = 0; nj_ < 2; nj_++)                          \
  _Pragma("unroll") for (int kk_ = 0; kk_ < 2; kk_++) {                        \
    const int r_ = (wcn & 1) * 64 + ((nbase) + nj_) * 16 + lrow;               \
    dst[nj_][kk_] = *(const s16x8*)&smem[buf][1][wcn >> 1]                     \
                        [r_ * 64 + ((kk_ * 4 + hi) ^ sx) * 8]; }

#define MM(mbase, nbase, areg, breg)                                           \
  _Pragma("unroll") for (int mi_ = 0; mi_ < 4; mi_++)                          \
  _Pragma("unroll") for (int nj_ = 0; nj_ < 2; nj_++)                          \
  _Pragma("unroll") for (int kk_ = 0; kk_ < 2; kk_++)                          \
    acc[(mbase) + mi_][(nbase) + nj_] = __builtin_amdgcn_mfma_f32_16x16x32_bf16( \
        breg[nj_][kk_], areg[mi_][kk_], acc[(mbase) + mi_][(nbase) + nj_], 0, 0, 0);

#define WLG  asm volatile("s_waitcnt lgkmcnt(0)" ::: "memory")
#define WVM8 asm volatile("s_waitcnt vmcnt(8)" ::: "memory")
#define WVM4 asm volatile("s_waitcnt vmcnt(4)" ::: "memory")
#define WVM0 asm volatile("s_waitcnt vmcnt(0)" ::: "memory")
#define BAR  __builtin_amdgcn_s_barrier()
#define PRIO1 __builtin_amdgcn_s_setprio(1)
#define PRIO0 __builtin_amdgcn_s_setprio(0)

  f32x4 acc[8][4] = {};
  const int NT  = K >> 6;
  const int NIT = NT >> 1;

  STG(0, 0, 0, 0, aBase); STG(0, 0, 1, 0, aBase);
  STG(0, 1, 0, 0, bBase); STG(0, 1, 1, 0, bBase);
  STG(1, 0, 0, 1, aBase); STG(1, 0, 1, 1, aBase);
  STG(1, 1, 0, 1, bBase); STG(1, 1, 1, 1, bBase);
  WVM8; BAR;

  for (int it = 0; it < NIT; ++it) {
    const int tE = 2 * it + 2, tO = 2 * it + 3;
    const bool pf = (tE < NT);
    s16x8 a[4][2], bl[2][2], bh[2][2];
    // PhA0: buf0 mlo x all-n | stage A(prev tO = 2it+1) -> buf1
    RDA(0, a, 0); RDB(0, bl, 0); RDB(0, bh, 2);
    if (it > 0) { STG(1, 0, 0, 2 * it + 1, aBase); STG(1, 0, 1, 2 * it + 1, aBase); }
    BAR; WLG;
    PRIO1; MM(0, 0, a, bl); MM(0, 2, a, bh); PRIO0;
    BAR;
    // PhB0: buf0 mhi x all-n | stage B(tE) -> buf0; vmcnt(4) drains buf1's tile
    RDA(0, a, 4);
    if (pf) { STG(0, 1, 0, tE, bBase); STG(0, 1, 1, tE, bBase); }
    BAR;
    if (pf) { WVM4; } else { WVM0; }
    WLG;
    PRIO1; MM(4, 0, a, bl); MM(4, 2, a, bh); PRIO0;
    BAR;
    // PhA1: buf1 mlo x all-n | stage A(tE) -> buf0
    RDA(1, a, 0); RDB(1, bl, 0); RDB(1, bh, 2);
    if (pf) { STG(0, 0, 0, tE, aBase); STG(0, 0, 1, tE, aBase); }
    BAR; WLG;
    PRIO1; MM(0, 0, a, bl); MM(0, 2, a, bh); PRIO0;
    BAR;
    // PhB1: buf1 mhi x all-n | stage B(tO) -> buf1; vmcnt(4) drains buf0's tE
    RDA(1, a, 4);
    if (pf) { STG(1, 1, 0, tO, bBase); STG(1, 1, 1, tO, bBase); }
    BAR;
    if (pf) { WVM4; } else { WVM0; }
    WLG;
    PRIO1; MM(4, 0, a, bl); MM(4, 2, a, bh); PRIO0;
    BAR;
  }

  const int mrow = m0 + wr * 128 + lrow;
  const int nb0  = n0 + wcn * 64 + (hi << 2);
#pragma unroll
  for (int mi = 0; mi < 8; mi++) {
    const int row = mrow + mi * 16;
#pragma unroll
    for (int nj = 0; nj < 4; nj++) {
      const int nb = nb0 + nj * 16;
      float v0 = acc[mi][nj][0], v1 = acc[mi][nj][1];
      float v2 = acc[mi][nj][2], v3 = acc[mi][nj][3];
      if (EPI == 1) {
        if (nb < 2 * DIM) {
          const int bb = nb & 63;
          v0 += bias[bb];     v1 += bias[bb + 1];
          v2 += bias[bb + 2]; v3 += bias[bb + 3];
          v0 = v0 > 0.f ? v0 : 0.f;  v1 = v1 > 0.f ? v1 : 0.f;
          v2 = v2 > 0.f ? v2 : 0.f;  v3 = v3 > 0.f ? v3 : 0.f;
        }
        uint2 st;
        st.x = (uint32_t)f2bf(v0) | ((uint32_t)f2bf(v1) << 16);
        st.y = (uint32_t)f2bf(v2) | ((uint32_t)f2bf(v3) << 16);
        *(uint2*)((u16*)Cout + (size_t)row * Nn + nb) = st;
      } else {
        float4 st;
        st.x = v0 + bias[nb];     st.y = v1 + bias[nb + 1];
        st.z = v2 + bias[nb + 2]; st.w = v3 + bias[nb + 3];
        *(float4*)((float*)Cout + (size_t)row * Nn + nb) = st;
      }
    }
  }
#undef STG
#undef RDA
#undef RDB
#undef MM
#undef WLG
#undef WVM8
#undef WVM4
#undef WVM0
#undef BAR
#undef PRIO1
#undef PRIO0
}

// ---------------- kv partials via MFMA (unchanged from R6) ----------------
__global__ __launch_bounds__(256) void kv_ksum_mfma(const u16* __restrict__ qkv,
                                                    float* __restrict__ kvpart,
                                                    float* __restrict__ kspart) {
  const int bh = blockIdx.x >> 3;
  const int chunk = blockIdx.x & 7;
  const int b = bh >> 4, h = bh & 15;
  __shared__ u16 kT[64 * 64];
  __shared__ u16 vT[80 * 64];
  const int tid  = threadIdx.x;
  const int lane = tid & 63;
  const int w    = tid >> 6;
  const int lrow = lane & 15;
  const int hi   = lane >> 4;

  for (int i = tid; i < 16 * 64; i += 256) {
    const int r = 64 + (i >> 6), n = i & 63;
    vT[r * 64 + (((n >> 3) ^ (r & 7)) << 3) + (n & 7)] = (r == 64) ? (u16)0x3F80 : (u16)0;
  }

  f32x4 acc[5] = {};
  const u16* kbase = qkv + (size_t)(b * SEQ) * NQKV + DIM     + h * DHEAD;
  const u16* vbase = qkv + (size_t)(b * SEQ) * NQKV + 2 * DIM + h * DHEAD;

  for (int r0 = chunk * 512; r0 < chunk * 512 + 512; r0 += 64) {
    __syncthreads();
    for (int s = tid; s < 512; s += 256) {
      const int r  = s >> 3;
      const int c0 = (s & 7) << 3;
      const s16x8 k8 = *(const s16x8*)(kbase + (size_t)(r0 + r) * NQKV + c0);
      const s16x8 v8 = *(const s16x8*)(vbase + (size_t)(r0 + r) * NQKV + c0);
      const int slot = r >> 3, nb = r & 7;
#pragma unroll
      for (int q = 0; q < 8; q++) {
        const int d = c0 + q;
        const int off = d * 64 + ((slot ^ (d & 7)) << 3) + nb;
        kT[off] = (u16)k8[q];
        vT[off] = (u16)v8[q];
      }
    }
    __syncthreads();
#pragma unroll
    for (int kk = 0; kk < 2; kk++) {
      const int drow = w * 16 + lrow;
      const s16x8 kf = *(const s16x8*)&kT[drow * 64 + (((kk * 4 + hi) ^ (drow & 7)) << 3)];
#pragma unroll
      for (int et = 0; et < 5; et++) {
        const int erow = et * 16 + lrow;
        const s16x8 vf = *(const s16x8*)&vT[erow * 64 + (((kk * 4 + hi) ^ (erow & 7)) << 3)];
        acc[et] = __builtin_amdgcn_mfma_f32_16x16x32_bf16(vf, kf, acc[et], 0, 0, 0);
      }
    }
  }

  const int d = w * 16 + lrow;
  float* outp = kvpart + (size_t)blockIdx.x * 4096;
#pragma unroll
  for (int et = 0; et < 4; et++)
    *(f32x4*)&outp[d * 64 + et * 16 + hi * 4] = acc[et];
  if (hi == 0) kspart[(size_t)blockIdx.x * 64 + d] = acc[4][0];
}

// ---------------- attn out via MFMA, self-reducing the 8 kv partials ----------------
// Staging sums kvpart[(bh*8+c)][d*64+e] over c=0..7 (same order reduce_kv used
// -> bit-identical). Partials are produced by the previous dispatch on the same
// stream, so plain loads are safe (no cross-XCD coherence hazard).
__global__ __launch_bounds__(256) void attn_mfma(const u16* __restrict__ qkv,
                                                 const float* __restrict__ kvpart,
                                                 const float* __restrict__ kspart,
                                                 u16* __restrict__ attn) {
  const int bh = blockIdx.x >> 4;
  const int mc = blockIdx.x & 15;
  const int b = bh >> 4, h = bh & 15;
  __shared__ u16 BT[2][80][64];
  __shared__ float nrm[256];
  const int tid  = threadIdx.x;
  const int lane = tid & 63;
  const int w    = tid >> 6;
  const int lrow = lane & 15;
  const int hi   = lane >> 4;

#pragma unroll
  for (int s = 0; s < 20; s++) {
    const int idx = tid + 256 * s;
    const int e = idx >> 6, d = idx & 63;
    float v = 0.f;
    if (e < 64) {
      const float* p = kvpart + (size_t)(bh * 8) * 4096 + d * 64 + e;
#pragma unroll
      for (int c = 0; c < 8; c++) v += p[(size_t)c * 4096];
    } else if (e == 64) {
      const float* p = kspart + bh * 8 * 64 + d;
#pragma unroll
      for (int c = 0; c < 8; c++) v += p[c * 64];
    }
    const u16 vh = f2bf(v);
    const u16 vl = f2bf(v - bf2f(vh));
    const int off = e * 64 + (((d >> 3) ^ (e & 7)) << 3) + (d & 7);
    BT[0][0][off] = vh;
    BT[1][0][off] = vl;
  }

  const int rloc = w * 64 + lrow;
  const u16* qbase = qkv + (size_t)(b * SEQ + mc * 256 + rloc) * NQKV + h * DHEAD + hi * 8;
  s16x8 af[4][2];
#pragma unroll
  for (int mi = 0; mi < 4; mi++)
#pragma unroll
    for (int kk = 0; kk < 2; kk++)
      af[mi][kk] = *(const s16x8*)(qbase + (size_t)(mi * 16) * NQKV + kk * 32);

  __syncthreads();

  f32x4 acc[4][5] = {};
#pragma unroll
  for (int wv = 0; wv < 2; wv++) {
#pragma unroll
    for (int jb = 0; jb < 5; jb++) {
      const int erow = jb * 16 + lrow;
      const int sx = erow & 7;
      s16x8 bq0 = *(const s16x8*)&BT[wv][erow][((0 * 4 + hi) ^ sx) << 3];
      s16x8 bq1 = *(const s16x8*)&BT[wv][erow][((1 * 4 + hi) ^ sx) << 3];
#pragma unroll
      for (int mi = 0; mi < 4; mi++) {
        acc[mi][jb] = __builtin_amdgcn_mfma_f32_16x16x32_bf16(bq0, af[mi][0], acc[mi][jb], 0, 0, 0);
        acc[mi][jb] = __builtin_amdgcn_mfma_f32_16x16x32_bf16(bq1, af[mi][1], acc[mi][jb], 0, 0, 0);
      }
    }
  }

  if (hi == 0) {
#pragma unroll
    for (int mi = 0; mi < 4; mi++) nrm[rloc + mi * 16] = acc[mi][4][0] + 1e-6f;
  }
  __syncthreads();

  u16* obase = attn + (size_t)(b * SEQ + mc * 256 + rloc) * DIM + h * DHEAD + hi * 4;
#pragma unroll
  for (int mi = 0; mi < 4; mi++) {
    const float sc = 1.f / nrm[rloc + mi * 16];
#pragma unroll
    for (int jb = 0; jb < 4; jb++) {
      uint2 st;
      st.x = (uint32_t)f2bf(acc[mi][jb][0] * sc) | ((uint32_t)f2bf(acc[mi][jb][1] * sc) << 16);
      st.y = (uint32_t)f2bf(acc[mi][jb][2] * sc) | ((uint32_t)f2bf(acc[mi][jb][3] * sc) << 16);
      *(uint2*)(obase + (size_t)(mi * 16) * DIM + jb * 16) = st;
    }
  }
}

extern "C" void kernel_launch(void* const* d_in, const int* in_sizes, int n_in,
                              void* d_out, int out_size, void* d_ws, size_t ws_size,
                              hipStream_t stream) {
  (void)in_sizes; (void)n_in; (void)out_size; (void)ws_size;
  const float* x     = (const float*)d_in[0];
  const float* Wqkv  = (const float*)d_in[1];
  const float* Wf    = (const float*)d_in[2];
  const float* bfv   = (const float*)d_in[3];
  const float* Wout  = (const float*)d_in[4];
  const float* bout  = (const float*)d_in[5];
  float* out = (float*)d_out;
  char* ws = (char*)d_ws;

  u16*   wqkvT = (u16*)(ws + 0);              // 3072*1024 bf16   = 6,291,456 B
  u16*   woutT = (u16*)(ws + 6291456);        // 1024*1024 bf16   = 2,097,152 B
  u16*   xb    = (u16*)(ws + 8388608);        // 16384*1024 bf16  = 33,554,432 B
  u16*   qkvb  = (u16*)(ws + 41943040);       // 16384*3072 bf16  = 100,663,296 B
  u16*   attn  = (u16*)(ws + 142606336);      // 16384*1024 bf16  = 33,554,432 B
  float* kvp   = (float*)(ws + 176160768);    // 512*4096 f32     = 8,388,608 B
  float* ksp   = (float*)(ws + 184549376);    // 512*64 f32       = 131,072 B

  prep<<<2816, 256, 0, stream>>>(x, Wqkv, Wf, Wout, xb, wqkvT, woutT);
  gemm4p<1><<<(MROWS / 256) * (NQKV / 256), 512, 0, stream>>>(xb, wqkvT, qkvb, bfv,
                                                              NQKV, DIM);
  kv_ksum_mfma<<<64 * 8, 256, 0, stream>>>(qkvb, kvp, ksp);
  attn_mfma<<<64 * 16, 256, 0, stream>>>(qkvb, kvp, ksp, attn);
  gemm4p<2><<<(MROWS / 256) * (DIM / 256), 512, 0, stream>>>(attn, woutT, out, bout,
                                                             DIM, DIM);
}

// Round 16
// 248.821 us; speedup vs baseline: 1.3836x; 1.3836x over previous
//
#include <hip/hip_runtime.h>
#include <hip/hip_bf16.h>
#include <stdint.h>

#define HEADS 16
#define DHEAD 64
#define DIM   1024
#define SEQ   4096
#define BATCH 4
#define MROWS (BATCH * SEQ)   // 16384
#define NQKV  (3 * DIM)       // 3072

typedef short  s16x8 __attribute__((ext_vector_type(8)));
typedef short  s16x4 __attribute__((ext_vector_type(4)));
typedef float  f32x4 __attribute__((ext_vector_type(4)));
typedef unsigned short u16;

__device__ __forceinline__ u16 f2bf(float f) {
  union { float f; uint32_t u; } v; v.f = f;
  uint32_t r = v.u + 0x7fffu + ((v.u >> 16) & 1u);  // RNE
  return (u16)(r >> 16);
}
__device__ __forceinline__ float bf2f(u16 h) {
  union { uint32_t u; float f; } v; v.u = ((uint32_t)h) << 16;
  return v.f;
}

// async global->LDS, 16B per lane; LDS dest is wave-uniform base + lane*16
__device__ __forceinline__ void gload_lds16(const void* g, void* l) {
  __builtin_amdgcn_global_load_lds((__attribute__((address_space(1))) void*)(g),
                                   (__attribute__((address_space(3))) void*)(l),
                                   16, 0, 0);
}

// ---------------- merged prologue: cast + fold_qk + 2x transpose_cast ----------------
// blocks 0..255    : fold W_f into q/k blocks of W_qkv (transposed bf16 out)
// blocks 256..511  : transpose+cast Wqkv v-columns -> wqkvT v region
// blocks 512..767  : transpose+cast Wout -> woutT
// blocks 768..2815 : cast x fp32 -> bf16 (grid-stride)
__global__ __launch_bounds__(256) void prep(const float* __restrict__ x,
                                            const float* __restrict__ Wqkv,
                                            const float* __restrict__ Wf,
                                            const float* __restrict__ Wout,
                                            u16* __restrict__ xb,
                                            u16* __restrict__ wqkvT,
                                            u16* __restrict__ woutT) {
  __shared__ __align__(16) char lds_raw[32768];
  const int bid = blockIdx.x;
  const int tid = threadIdx.x;

  if (bid < 256) {
    // ---- fold_qk (R6-proven body) ----
    float* wc = (float*)lds_raw;              // 128*64 fp32 = 32 KB
    const int rh  = bid >> 3;                 // 0..31 = (reg,h)
    const int kc  = (bid & 7) << 7;           // k-chunk base (128 each)
    const int reg = rh >> 4, h = rh & 15;
    const int base = reg * DIM + h * DHEAD;
    const int j  = tid & 63;
    const int kg = tid >> 6;
    for (int i = tid; i < 128 * 16; i += 256) {
      const int r = i >> 4, c4 = (i & 15) << 2;
      *(float4*)&wc[r * 64 + c4] = *(const float4*)&Wqkv[(size_t)(kc + r) * NQKV + base + c4];
    }
    float v[64];
#pragma unroll
    for (int d = 0; d < 64; d++) v[d] = Wf[d * 64 + j];
    __syncthreads();
    u16* dst = wqkvT + (size_t)(base + j) * DIM + kc + kg * 32;
    for (int ki = 0; ki < 32; ki++) {
      const int k = kg * 32 + ki;
      float s = 0.f;
#pragma unroll
      for (int d = 0; d < 64; d++) s += wc[k * 64 + d] * v[d];
      dst[ki] = f2bf(s);
    }
  } else if (bid < 768) {
    // ---- transpose_cast (two instances) ----
    float (*t)[65] = (float(*)[65])lds_raw;   // 64*65 fp32 = 16.6 KB
    const float* src;
    int srcStride, colOff;
    u16* dst;
    int tile = bid & 255;
    if (bid < 512) { src = Wqkv; srcStride = NQKV; colOff = 2 * DIM;
                     dst = wqkvT + (size_t)2 * DIM * DIM; }
    else           { src = Wout; srcStride = DIM;  colOff = 0; dst = woutT; }
    const int ntiles = DIM >> 6;              // 16
    const int n0 = (tile % ntiles) * 64;
    const int k0 = (tile / ntiles) * 64;
    for (int i = tid; i < 4096; i += 256) {
      const int r = i >> 6, c = i & 63;
      t[r][c] = src[(size_t)(k0 + r) * srcStride + colOff + n0 + c];
    }
    __syncthreads();
    for (int i = tid; i < 4096; i += 256) {
      const int r = i & 63, c = i >> 6;
      dst[(size_t)(n0 + c) * DIM + k0 + r] = f2bf(t[r][c]);
    }
  } else {
    // ---- cast x fp32 -> bf16 ----
    const int n = MROWS * DIM;
    int i = ((bid - 768) * 256 + tid) * 4;
    const int stride = 2048 * 256 * 4;
    for (; i < n; i += stride) {
      float4 f = *(const float4*)(x + i);
      ushort4 o;
      o.x = f2bf(f.x); o.y = f2bf(f.y); o.z = f2bf(f.z); o.w = f2bf(f.w);
      *(ushort4*)(xb + i) = o;
    }
  }
}

// ---------------- 256x256 4-phase MFMA GEMM (R9/R12 proven) ----------------
// Each phase = one m-row (mlo/mhi) x all n = 32 MFMAs. Stage placement by
// region-phase rule; vmcnt(4) at PhB0/PhB1 drains exactly the 8 ops of the
// buffer read next phase. A via gload_lds with pre-swizzled source.
template <int EPI>
__global__ __launch_bounds__(512, 2) void gemm4p(const u16* __restrict__ A,
                                                 const u16* __restrict__ Bt,
                                                 void* __restrict__ Cout,
                                                 const float* __restrict__ bias,
                                                 int Nn, int K) {
  __shared__ __align__(16) u16 smem[2][2][2][128 * 64];  // [buf][A0/B1][half] = 128 KiB
  const int tilesN = Nn >> 8;
  const int cpx   = gridDim.x >> 3;
  const int xcd   = blockIdx.x & 7;
  const int local = blockIdx.x >> 3;
  const int bmPerX = cpx / tilesN;
  const int perG = 4 * tilesN;
  const int g = local / perG, rrm = local % perG;
  const int bm = xcd * bmPerX + g * 4 + rrm / tilesN;
  const int bn = rrm % tilesN;
  const int m0 = bm << 8, n0 = bn << 8;

  const int tid  = threadIdx.x;
  const int lane = tid & 63;
  const int w    = tid >> 6;
  const int wr = w >> 2, wcn = w & 3;
  const int lrow = lane & 15;
  const int hi   = lane >> 4;
  const int sx   = lrow & 7;

  const int srow  = tid >> 3;
  const int pslot = tid & 7;
  const int gk    = (pslot ^ (srow & 7)) << 3;
  const u16* aBase = A  + (size_t)m0 * K + gk;
  const u16* bBase = Bt + (size_t)n0 * K + gk;

#define STG(buf, op, half, kt, gb)                                             \
  { const u16* s0_ = (gb) + (size_t)((half) * 128 + srow) * K + (kt) * 64;     \
    char* d0_ = (char*)&smem[buf][op][half][0] + tid * 16;                     \
    gload_lds16(s0_, d0_);                                                     \
    gload_lds16(s0_ + (size_t)64 * K, d0_ + 8192); }

#define RDA(buf, dst, mbase)                                                   \
  _Pragma("unroll") for (int mi_ = 0; mi_ < 4; mi_++)                          \
  _Pragma("unroll") for (int kk_ = 0; kk_ < 2; kk_++) {                        \
    const int r_ = ((mbase) + mi_) * 16 + lrow;                                \
    dst[mi_][kk_] = *(const s16x8*)&smem[buf][0][wr]                           \
                        [r_ * 64 + ((kk_ * 4 + hi) ^ sx) * 8]; }

#define RDB(buf, dst, nbase)                                                   \
  _Pragma("unroll") for (int nj_ = 0; nj_ < 2; nj_++)                          \
  _Pragma("unroll") for (int kk_ = 0; kk_ < 2; kk_++) {                        \
    const int r_ = (wcn & 1) * 64 + ((nbase) + nj_) * 16 + lrow;               \
    dst[nj_][kk_] = *(const s16x8*)&smem[buf][1][wcn >> 1]                     \
                        [r_ * 64 + ((kk_ * 4 + hi) ^ sx) * 8]; }

#define MM(mbase, nbase, areg, breg)                                           \
  _Pragma("unroll") for (int mi_ = 0; mi_ < 4; mi_++)                          \
  _Pragma("unroll") for (int nj_ = 0; nj_ < 2; nj_++)                          \
  _Pragma("unroll") for (int kk_ = 0; kk_ < 2; kk_++)                          \
    acc[(mbase) + mi_][(nbase) + nj_] = __builtin_amdgcn_mfma_f32_16x16x32_bf16( \
        breg[nj_][kk_], areg[mi_][kk_], acc[(mbase) + mi_][(nbase) + nj_], 0, 0, 0);

#define WLG  asm volatile("s_waitcnt lgkmcnt(0)" ::: "memory")
#define WVM8 asm volatile("s_waitcnt vmcnt(8)" ::: "memory")
#define WVM4 asm volatile("s_waitcnt vmcnt(4)" ::: "memory")
#define WVM0 asm volatile("s_waitcnt vmcnt(0)" ::: "memory")
#define BAR  __builtin_amdgcn_s_barrier()
#define PRIO1 __builtin_amdgcn_s_setprio(1)
#define PRIO0 __builtin_amdgcn_s_setprio(0)

  f32x4 acc[8][4] = {};
  const int NT  = K >> 6;
  const int NIT = NT >> 1;

  STG(0, 0, 0, 0, aBase); STG(0, 0, 1, 0, aBase);
  STG(0, 1, 0, 0, bBase); STG(0, 1, 1, 0, bBase);
  STG(1, 0, 0, 1, aBase); STG(1, 0, 1, 1, aBase);
  STG(1, 1, 0, 1, bBase); STG(1, 1, 1, 1, bBase);
  WVM8; BAR;

  for (int it = 0; it < NIT; ++it) {
    const int tE = 2 * it + 2, tO = 2 * it + 3;
    const bool pf = (tE < NT);
    s16x8 a[4][2], bl[2][2], bh[2][2];
    // PhA0: buf0 mlo x all-n | stage A(prev tO = 2it+1) -> buf1
    RDA(0, a, 0); RDB(0, bl, 0); RDB(0, bh, 2);
    if (it > 0) { STG(1, 0, 0, 2 * it + 1, aBase); STG(1, 0, 1, 2 * it + 1, aBase); }
    BAR; WLG;
    PRIO1; MM(0, 0, a, bl); MM(0, 2, a, bh); PRIO0;
    BAR;
    // PhB0: buf0 mhi x all-n | stage B(tE) -> buf0; vmcnt(4) drains buf1's tile
    RDA(0, a, 4);
    if (pf) { STG(0, 1, 0, tE, bBase); STG(0, 1, 1, tE, bBase); }
    BAR;
    if (pf) { WVM4; } else { WVM0; }
    WLG;
    PRIO1; MM(4, 0, a, bl); MM(4, 2, a, bh); PRIO0;
    BAR;
    // PhA1: buf1 mlo x all-n | stage A(tE) -> buf0
    RDA(1, a, 0); RDB(1, bl, 0); RDB(1, bh, 2);
    if (pf) { STG(0, 0, 0, tE, aBase); STG(0, 0, 1, tE, aBase); }
    BAR; WLG;
    PRIO1; MM(0, 0, a, bl); MM(0, 2, a, bh); PRIO0;
    BAR;
    // PhB1: buf1 mhi x all-n | stage B(tO) -> buf1; vmcnt(4) drains buf0's tE
    RDA(1, a, 4);
    if (pf) { STG(1, 1, 0, tO, bBase); STG(1, 1, 1, tO, bBase); }
    BAR;
    if (pf) { WVM4; } else { WVM0; }
    WLG;
    PRIO1; MM(4, 0, a, bl); MM(4, 2, a, bh); PRIO0;
    BAR;
  }

  const int mrow = m0 + wr * 128 + lrow;
  const int nb0  = n0 + wcn * 64 + (hi << 2);
#pragma unroll
  for (int mi = 0; mi < 8; mi++) {
    const int row = mrow + mi * 16;
#pragma unroll
    for (int nj = 0; nj < 4; nj++) {
      const int nb = nb0 + nj * 16;
      float v0 = acc[mi][nj][0], v1 = acc[mi][nj][1];
      float v2 = acc[mi][nj][2], v3 = acc[mi][nj][3];
      if (EPI == 1) {
        if (nb < 2 * DIM) {
          const int bb = nb & 63;
          v0 += bias[bb];     v1 += bias[bb + 1];
          v2 += bias[bb + 2]; v3 += bias[bb + 3];
          v0 = v0 > 0.f ? v0 : 0.f;  v1 = v1 > 0.f ? v1 : 0.f;
          v2 = v2 > 0.f ? v2 : 0.f;  v3 = v3 > 0.f ? v3 : 0.f;
        }
        uint2 st;
        st.x = (uint32_t)f2bf(v0) | ((uint32_t)f2bf(v1) << 16);
        st.y = (uint32_t)f2bf(v2) | ((uint32_t)f2bf(v3) << 16);
        *(uint2*)((u16*)Cout + (size_t)row * Nn + nb) = st;
      } else {
        float4 st;
        st.x = v0 + bias[nb];     st.y = v1 + bias[nb + 1];
        st.z = v2 + bias[nb + 2]; st.w = v3 + bias[nb + 3];
        *(float4*)((float*)Cout + (size_t)row * Nn + nb) = st;
      }
    }
  }
#undef STG
#undef RDA
#undef RDB
#undef MM
#undef WLG
#undef WVM8
#undef WVM4
#undef WVM0
#undef BAR
#undef PRIO1
#undef PRIO0
}

// ---------------- kv partials via MFMA (unchanged from R6) ----------------
__global__ __launch_bounds__(256) void kv_ksum_mfma(const u16* __restrict__ qkv,
                                                    float* __restrict__ kvpart,
                                                    float* __restrict__ kspart) {
  const int bh = blockIdx.x >> 3;
  const int chunk = blockIdx.x & 7;
  const int b = bh >> 4, h = bh & 15;
  __shared__ u16 kT[64 * 64];
  __shared__ u16 vT[80 * 64];
  const int tid  = threadIdx.x;
  const int lane = tid & 63;
  const int w    = tid >> 6;
  const int lrow = lane & 15;
  const int hi   = lane >> 4;

  for (int i = tid; i < 16 * 64; i += 256) {
    const int r = 64 + (i >> 6), n = i & 63;
    vT[r * 64 + (((n >> 3) ^ (r & 7)) << 3) + (n & 7)] = (r == 64) ? (u16)0x3F80 : (u16)0;
  }

  f32x4 acc[5] = {};
  const u16* kbase = qkv + (size_t)(b * SEQ) * NQKV + DIM     + h * DHEAD;
  const u16* vbase = qkv + (size_t)(b * SEQ) * NQKV + 2 * DIM + h * DHEAD;

  for (int r0 = chunk * 512; r0 < chunk * 512 + 512; r0 += 64) {
    __syncthreads();
    for (int s = tid; s < 512; s += 256) {
      const int r  = s >> 3;
      const int c0 = (s & 7) << 3;
      const s16x8 k8 = *(const s16x8*)(kbase + (size_t)(r0 + r) * NQKV + c0);
      const s16x8 v8 = *(const s16x8*)(vbase + (size_t)(r0 + r) * NQKV + c0);
      const int slot = r >> 3, nb = r & 7;
#pragma unroll
      for (int q = 0; q < 8; q++) {
        const int d = c0 + q;
        const int off = d * 64 + ((slot ^ (d & 7)) << 3) + nb;
        kT[off] = (u16)k8[q];
        vT[off] = (u16)v8[q];
      }
    }
    __syncthreads();
#pragma unroll
    for (int kk = 0; kk < 2; kk++) {
      const int drow = w * 16 + lrow;
      const s16x8 kf = *(const s16x8*)&kT[drow * 64 + (((kk * 4 + hi) ^ (drow & 7)) << 3)];
#pragma unroll
      for (int et = 0; et < 5; et++) {
        const int erow = et * 16 + lrow;
        const s16x8 vf = *(const s16x8*)&vT[erow * 64 + (((kk * 4 + hi) ^ (erow & 7)) << 3)];
        acc[et] = __builtin_amdgcn_mfma_f32_16x16x32_bf16(vf, kf, acc[et], 0, 0, 0);
      }
    }
  }

  const int d = w * 16 + lrow;
  float* outp = kvpart + (size_t)blockIdx.x * 4096;
#pragma unroll
  for (int et = 0; et < 4; et++)
    *(f32x4*)&outp[d * 64 + et * 16 + hi * 4] = acc[et];
  if (hi == 0) kspart[(size_t)blockIdx.x * 64 + d] = acc[4][0];
}

// ---------------- deterministic partial reduction ----------------
__global__ __launch_bounds__(256) void reduce_kv(const float* __restrict__ kvpart,
                                                 const float* __restrict__ kspart,
                                                 float* __restrict__ kvbuf,
                                                 float* __restrict__ ksumb) {
  const int idx = blockIdx.x * 256 + threadIdx.x;
  if (idx < 64 * 4096) {
    const int bh = idx >> 12, i = idx & 4095;
    float s = 0.f;
#pragma unroll
    for (int c = 0; c < 8; c++) s += kvpart[(size_t)((bh << 3) + c) * 4096 + i];
    kvbuf[idx] = s;
  } else {
    const int idx2 = idx - 64 * 4096;
    if (idx2 < 4096) {
      const int bh = idx2 >> 6, i = idx2 & 63;
      float s = 0.f;
#pragma unroll
      for (int c = 0; c < 8; c++) s += kspart[((bh << 3) + c) * 64 + i];
      ksumb[idx2] = s;
    }
  }
}

// ---------------- attn out via MFMA (R5/R12 proven) ----------------
__global__ __launch_bounds__(256) void attn_mfma(const u16* __restrict__ qkv,
                                                 const float* __restrict__ kvbuf,
                                                 const float* __restrict__ ksumb,
                                                 u16* __restrict__ attn) {
  const int bh = blockIdx.x >> 4;
  const int mc = blockIdx.x & 15;
  const int b = bh >> 4, h = bh & 15;
  __shared__ u16 BT[2][80][64];
  __shared__ float nrm[256];
  const int tid  = threadIdx.x;
  const int lane = tid & 63;
  const int w    = tid >> 6;
  const int lrow = lane & 15;
  const int hi   = lane >> 4;

#pragma unroll
  for (int s = 0; s < 20; s++) {
    const int idx = tid + 256 * s;
    const int e = idx >> 6, d = idx & 63;
    float v;
    if (e < 64)       v = kvbuf[(size_t)bh * 4096 + d * 64 + e];
    else if (e == 64) v = ksumb[bh * 64 + d];
    else              v = 0.f;
    const u16 vh = f2bf(v);
    const u16 vl = f2bf(v - bf2f(vh));
    const int off = e * 64 + (((d >> 3) ^ (e & 7)) << 3) + (d & 7);
    BT[0][0][off] = vh;
    BT[1][0][off] = vl;
  }

  const int rloc = w * 64 + lrow;
  const u16* qbase = qkv + (size_t)(b * SEQ + mc * 256 + rloc) * NQKV + h * DHEAD + hi * 8;
  s16x8 af[4][2];
#pragma unroll
  for (int mi = 0; mi < 4; mi++)
#pragma unroll
    for (int kk = 0; kk < 2; kk++)
      af[mi][kk] = *(const s16x8*)(qbase + (size_t)(mi * 16) * NQKV + kk * 32);

  __syncthreads();

  f32x4 acc[4][5] = {};
#pragma unroll
  for (int wv = 0; wv < 2; wv++) {
#pragma unroll
    for (int jb = 0; jb < 5; jb++) {
      const int erow = jb * 16 + lrow;
      const int sx = erow & 7;
      s16x8 bq0 = *(const s16x8*)&BT[wv][erow][((0 * 4 + hi) ^ sx) << 3];
      s16x8 bq1 = *(const s16x8*)&BT[wv][erow][((1 * 4 + hi) ^ sx) << 3];
#pragma unroll
      for (int mi = 0; mi < 4; mi++) {
        acc[mi][jb] = __builtin_amdgcn_mfma_f32_16x16x32_bf16(bq0, af[mi][0], acc[mi][jb], 0, 0, 0);
        acc[mi][jb] = __builtin_amdgcn_mfma_f32_16x16x32_bf16(bq1, af[mi][1], acc[mi][jb], 0, 0, 0);
      }
    }
  }

  if (hi == 0) {
#pragma unroll
    for (int mi = 0; mi < 4; mi++) nrm[rloc + mi * 16] = acc[mi][4][0] + 1e-6f;
  }
  __syncthreads();

  u16* obase = attn + (size_t)(b * SEQ + mc * 256 + rloc) * DIM + h * DHEAD + hi * 4;
#pragma unroll
  for (int mi = 0; mi < 4; mi++) {
    const float sc = 1.f / nrm[rloc + mi * 16];
#pragma unroll
    for (int jb = 0; jb < 4; jb++) {
      uint2 st;
      st.x = (uint32_t)f2bf(acc[mi][jb][0] * sc) | ((uint32_t)f2bf(acc[mi][jb][1] * sc) << 16);
      st.y = (uint32_t)f2bf(acc[mi][jb][2] * sc) | ((uint32_t)f2bf(acc[mi][jb][3] * sc) << 16);
      *(uint2*)(obase + (size_t)(mi * 16) * DIM + jb * 16) = st;
    }
  }
}

extern "C" void kernel_launch(void* const* d_in, const int* in_sizes, int n_in,
                              void* d_out, int out_size, void* d_ws, size_t ws_size,
                              hipStream_t stream) {
  (void)in_sizes; (void)n_in; (void)out_size; (void)ws_size;
  const float* x     = (const float*)d_in[0];
  const float* Wqkv  = (const float*)d_in[1];
  const float* Wf    = (const float*)d_in[2];
  const float* bfv   = (const float*)d_in[3];
  const float* Wout  = (const float*)d_in[4];
  const float* bout  = (const float*)d_in[5];
  float* out = (float*)d_out;
  char* ws = (char*)d_ws;

  u16*   wqkvT = (u16*)(ws + 0);              // 3072*1024 bf16   = 6,291,456 B
  u16*   woutT = (u16*)(ws + 6291456);        // 1024*1024 bf16   = 2,097,152 B
  u16*   xb    = (u16*)(ws + 8388608);        // 16384*1024 bf16  = 33,554,432 B
  u16*   qkvb  = (u16*)(ws + 41943040);       // 16384*3072 bf16  = 100,663,296 B
  u16*   attn  = (u16*)(ws + 142606336);      // 16384*1024 bf16  = 33,554,432 B
  float* kvp   = (float*)(ws + 176160768);    // 512*4096 f32     = 8,388,608 B
  float* ksp   = (float*)(ws + 184549376);    // 512*64 f32       = 131,072 B
  float* kvbuf = (float*)(ws + 184680448);    // 64*4096 f32      = 1,048,576 B
  float* ksumb = (float*)(ws + 185729024);    // 64*64 f32        = 16,384 B

  prep<<<2816, 256, 0, stream>>>(x, Wqkv, Wf, Wout, xb, wqkvT, woutT);
  gemm4p<1><<<(MROWS / 256) * (NQKV / 256), 512, 0, stream>>>(xb, wqkvT, qkvb, bfv,
                                                              NQKV, DIM);
  kv_ksum_mfma<<<64 * 8, 256, 0, stream>>>(qkvb, kvp, ksp);
  reduce_kv<<<(64 * 4096 + 64 * 64 + 255) / 256, 256, 0, stream>>>(kvp, ksp, kvbuf, ksumb);
  attn_mfma<<<64 * 16, 256, 0, stream>>>(qkvb, kvbuf, ksumb, attn);
  gemm4p<2><<<(MROWS / 256) * (DIM / 256), 512, 0, stream>>>(attn, woutT, out, bout,
                                                             DIM, DIM);
}

// Round 17
// 242.987 us; speedup vs baseline: 1.4168x; 1.0240x over previous
//
#include <hip/hip_runtime.h>
#include <hip/hip_bf16.h>
#include <stdint.h>

#define HEADS 16
#define DHEAD 64
#define DIM   1024
#define SEQ   4096
#define BATCH 4
#define MROWS (BATCH * SEQ)   // 16384
#define NQKV  (3 * DIM)       // 3072

typedef short  s16x8 __attribute__((ext_vector_type(8)));
typedef short  s16x4 __attribute__((ext_vector_type(4)));
typedef float  f32x4 __attribute__((ext_vector_type(4)));
typedef unsigned short u16;

__device__ __forceinline__ u16 f2bf(float f) {
  union { float f; uint32_t u; } v; v.f = f;
  uint32_t r = v.u + 0x7fffu + ((v.u >> 16) & 1u);  // RNE
  return (u16)(r >> 16);
}
__device__ __forceinline__ float bf2f(u16 h) {
  union { uint32_t u; float f; } v; v.u = ((uint32_t)h) << 16;
  return v.f;
}

// async global->LDS, 16B per lane; LDS dest is wave-uniform base + lane*16
__device__ __forceinline__ void gload_lds16(const void* g, void* l) {
  __builtin_amdgcn_global_load_lds((__attribute__((address_space(1))) void*)(g),
                                   (__attribute__((address_space(3))) void*)(l),
                                   16, 0, 0);
}

// ---------------- merged prologue: cast + fold_qk + 2x transpose_cast ----------------
// blocks 0..255    : fold W_f into q/k blocks of W_qkv (transposed bf16 out)
// blocks 256..511  : transpose+cast Wqkv v-columns -> wqkvT v region
// blocks 512..767  : transpose+cast Wout -> woutT
// blocks 768..2815 : cast x fp32 -> bf16 (grid-stride)
__global__ __launch_bounds__(256) void prep(const float* __restrict__ x,
                                            const float* __restrict__ Wqkv,
                                            const float* __restrict__ Wf,
                                            const float* __restrict__ Wout,
                                            u16* __restrict__ xb,
                                            u16* __restrict__ wqkvT,
                                            u16* __restrict__ woutT) {
  __shared__ __align__(16) char lds_raw[32768];
  const int bid = blockIdx.x;
  const int tid = threadIdx.x;

  if (bid < 256) {
    // ---- fold_qk (R6-proven body) ----
    float* wc = (float*)lds_raw;              // 128*64 fp32 = 32 KB
    const int rh  = bid >> 3;                 // 0..31 = (reg,h)
    const int kc  = (bid & 7) << 7;           // k-chunk base (128 each)
    const int reg = rh >> 4, h = rh & 15;
    const int base = reg * DIM + h * DHEAD;
    const int j  = tid & 63;
    const int kg = tid >> 6;
    for (int i = tid; i < 128 * 16; i += 256) {
      const int r = i >> 4, c4 = (i & 15) << 2;
      *(float4*)&wc[r * 64 + c4] = *(const float4*)&Wqkv[(size_t)(kc + r) * NQKV + base + c4];
    }
    float v[64];
#pragma unroll
    for (int d = 0; d < 64; d++) v[d] = Wf[d * 64 + j];
    __syncthreads();
    u16* dst = wqkvT + (size_t)(base + j) * DIM + kc + kg * 32;
    for (int ki = 0; ki < 32; ki++) {
      const int k = kg * 32 + ki;
      float s = 0.f;
#pragma unroll
      for (int d = 0; d < 64; d++) s += wc[k * 64 + d] * v[d];
      dst[ki] = f2bf(s);
    }
  } else if (bid < 768) {
    // ---- transpose_cast (two instances) ----
    float (*t)[65] = (float(*)[65])lds_raw;   // 64*65 fp32 = 16.6 KB
    const float* src;
    int srcStride, colOff;
    u16* dst;
    int tile = bid & 255;
    if (bid < 512) { src = Wqkv; srcStride = NQKV; colOff = 2 * DIM;
                     dst = wqkvT + (size_t)2 * DIM * DIM; }
    else           { src = Wout; srcStride = DIM;  colOff = 0; dst = woutT; }
    const int ntiles = DIM >> 6;              // 16
    const int n0 = (tile % ntiles) * 64;
    const int k0 = (tile / ntiles) * 64;
    for (int i = tid; i < 4096; i += 256) {
      const int r = i >> 6, c = i & 63;
      t[r][c] = src[(size_t)(k0 + r) * srcStride + colOff + n0 + c];
    }
    __syncthreads();
    for (int i = tid; i < 4096; i += 256) {
      const int r = i & 63, c = i >> 6;
      dst[(size_t)(n0 + c) * DIM + k0 + r] = f2bf(t[r][c]);
    }
  } else {
    // ---- cast x fp32 -> bf16 ----
    const int n = MROWS * DIM;
    int i = ((bid - 768) * 256 + tid) * 4;
    const int stride = 2048 * 256 * 4;
    for (; i < n; i += stride) {
      float4 f = *(const float4*)(x + i);
      ushort4 o;
      o.x = f2bf(f.x); o.y = f2bf(f.y); o.z = f2bf(f.z); o.w = f2bf(f.w);
      *(ushort4*)(xb + i) = o;
    }
  }
}

// ---------------- 256x256 4-phase MFMA GEMM (R9/R12 proven) ----------------
// Each phase = one m-row (mlo/mhi) x all n = 32 MFMAs. Stage placement by
// region-phase rule; vmcnt(4) at PhB0/PhB1 drains exactly the 8 ops of the
// buffer read next phase. A via gload_lds with pre-swizzled source.
template <int EPI>
__global__ __launch_bounds__(512, 2) void gemm4p(const u16* __restrict__ A,
                                                 const u16* __restrict__ Bt,
                                                 void* __restrict__ Cout,
                                                 const float* __restrict__ bias,
                                                 int Nn, int K) {
  __shared__ __align__(16) u16 smem[2][2][2][128 * 64];  // [buf][A0/B1][half] = 128 KiB
  const int tilesN = Nn >> 8;
  const int cpx   = gridDim.x >> 3;
  const int xcd   = blockIdx.x & 7;
  const int local = blockIdx.x >> 3;
  const int bmPerX = cpx / tilesN;
  const int perG = 4 * tilesN;
  const int g = local / perG, rrm = local % perG;
  const int bm = xcd * bmPerX + g * 4 + rrm / tilesN;
  const int bn = rrm % tilesN;
  const int m0 = bm << 8, n0 = bn << 8;

  const int tid  = threadIdx.x;
  const int lane = tid & 63;
  const int w    = tid >> 6;
  const int wr = w >> 2, wcn = w & 3;
  const int lrow = lane & 15;
  const int hi   = lane >> 4;
  const int sx   = lrow & 7;

  const int srow  = tid >> 3;
  const int pslot = tid & 7;
  const int gk    = (pslot ^ (srow & 7)) << 3;
  const u16* aBase = A  + (size_t)m0 * K + gk;
  const u16* bBase = Bt + (size_t)n0 * K + gk;

#define STG(buf, op, half, kt, gb)                                             \
  { const u16* s0_ = (gb) + (size_t)((half) * 128 + srow) * K + (kt) * 64;     \
    char* d0_ = (char*)&smem[buf][op][half][0] + tid * 16;                     \
    gload_lds16(s0_, d0_);                                                     \
    gload_lds16(s0_ + (size_t)64 * K, d0_ + 8192); }

#define RDA(buf, dst, mbase)                                                   \
  _Pragma("unroll") for (int mi_ = 0; mi_ < 4; mi_++)                          \
  _Pragma("unroll") for (int kk_ = 0; kk_ < 2; kk_++) {                        \
    const int r_ = ((mbase) + mi_) * 16 + lrow;                                \
    dst[mi_][kk_] = *(const s16x8*)&smem[buf][0][wr]                           \
                        [r_ * 64 + ((kk_ * 4 + hi) ^ sx) * 8]; }

#define RDB(buf, dst, nbase)                                                   \
  _Pragma("unroll") for (int nj_ = 0; nj_ < 2; nj_++)                          \
  _Pragma("unroll") for (int kk_ = 0; kk_ < 2; kk_++) {                        \
    const int r_ = (wcn & 1) * 64 + ((nbase) + nj_) * 16 + lrow;               \
    dst[nj_][kk_] = *(const s16x8*)&smem[buf][1][wcn >> 1]                     \
                        [r_ * 64 + ((kk_ * 4 + hi) ^ sx) * 8]; }

#define MM(mbase, nbase, areg, breg)                                           \
  _Pragma("unroll") for (int mi_ = 0; mi_ < 4; mi_++)                          \
  _Pragma("unroll") for (int nj_ = 0; nj_ < 2; nj_++)                          \
  _Pragma("unroll") for (int kk_ = 0; kk_ < 2; kk_++)                          \
    acc[(mbase) + mi_][(nbase) + nj_] = __builtin_amdgcn_mfma_f32_16x16x32_bf16( \
        breg[nj_][kk_], areg[mi_][kk_], acc[(mbase) + mi_][(nbase) + nj_], 0, 0, 0);

#define WLG  asm volatile("s_waitcnt lgkmcnt(0)" ::: "memory")
#define WVM8 asm volatile("s_waitcnt vmcnt(8)" ::: "memory")
#define WVM4 asm volatile("s_waitcnt vmcnt(4)" ::: "memory")
#define WVM0 asm volatile("s_waitcnt vmcnt(0)" ::: "memory")
#define BAR  __builtin_amdgcn_s_barrier()
#define PRIO1 __builtin_amdgcn_s_setprio(1)
#define PRIO0 __builtin_amdgcn_s_setprio(0)

  f32x4 acc[8][4] = {};
  const int NT  = K >> 6;
  const int NIT = NT >> 1;

  STG(0, 0, 0, 0, aBase); STG(0, 0, 1, 0, aBase);
  STG(0, 1, 0, 0, bBase); STG(0, 1, 1, 0, bBase);
  STG(1, 0, 0, 1, aBase); STG(1, 0, 1, 1, aBase);
  STG(1, 1, 0, 1, bBase); STG(1, 1, 1, 1, bBase);
  WVM8; BAR;

  for (int it = 0; it < NIT; ++it) {
    const int tE = 2 * it + 2, tO = 2 * it + 3;
    const bool pf = (tE < NT);
    s16x8 a[4][2], bl[2][2], bh[2][2];
    // PhA0: buf0 mlo x all-n | stage A(prev tO = 2it+1) -> buf1
    RDA(0, a, 0); RDB(0, bl, 0); RDB(0, bh, 2);
    if (it > 0) { STG(1, 0, 0, 2 * it + 1, aBase); STG(1, 0, 1, 2 * it + 1, aBase); }
    BAR; WLG;
    PRIO1; MM(0, 0, a, bl); MM(0, 2, a, bh); PRIO0;
    BAR;
    // PhB0: buf0 mhi x all-n | stage B(tE) -> buf0; vmcnt(4) drains buf1's tile
    RDA(0, a, 4);
    if (pf) { STG(0, 1, 0, tE, bBase); STG(0, 1, 1, tE, bBase); }
    BAR;
    if (pf) { WVM4; } else { WVM0; }
    WLG;
    PRIO1; MM(4, 0, a, bl); MM(4, 2, a, bh); PRIO0;
    BAR;
    // PhA1: buf1 mlo x all-n | stage A(tE) -> buf0
    RDA(1, a, 0); RDB(1, bl, 0); RDB(1, bh, 2);
    if (pf) { STG(0, 0, 0, tE, aBase); STG(0, 0, 1, tE, aBase); }
    BAR; WLG;
    PRIO1; MM(0, 0, a, bl); MM(0, 2, a, bh); PRIO0;
    BAR;
    // PhB1: buf1 mhi x all-n | stage B(tO) -> buf1; vmcnt(4) drains buf0's tE
    RDA(1, a, 4);
    if (pf) { STG(1, 1, 0, tO, bBase); STG(1, 1, 1, tO, bBase); }
    BAR;
    if (pf) { WVM4; } else { WVM0; }
    WLG;
    PRIO1; MM(4, 0, a, bl); MM(4, 2, a, bh); PRIO0;
    BAR;
  }

  const int mrow = m0 + wr * 128 + lrow;
  const int nb0  = n0 + wcn * 64 + (hi << 2);
#pragma unroll
  for (int mi = 0; mi < 8; mi++) {
    const int row = mrow + mi * 16;
#pragma unroll
    for (int nj = 0; nj < 4; nj++) {
      const int nb = nb0 + nj * 16;
      float v0 = acc[mi][nj][0], v1 = acc[mi][nj][1];
      float v2 = acc[mi][nj][2], v3 = acc[mi][nj][3];
      if (EPI == 1) {
        if (nb < 2 * DIM) {
          const int bb = nb & 63;
          v0 += bias[bb];     v1 += bias[bb + 1];
          v2 += bias[bb + 2]; v3 += bias[bb + 3];
          v0 = v0 > 0.f ? v0 : 0.f;  v1 = v1 > 0.f ? v1 : 0.f;
          v2 = v2 > 0.f ? v2 : 0.f;  v3 = v3 > 0.f ? v3 : 0.f;
        }
        uint2 st;
        st.x = (uint32_t)f2bf(v0) | ((uint32_t)f2bf(v1) << 16);
        st.y = (uint32_t)f2bf(v2) | ((uint32_t)f2bf(v3) << 16);
        *(uint2*)((u16*)Cout + (size_t)row * Nn + nb) = st;
      } else {
        float4 st;
        st.x = v0 + bias[nb];     st.y = v1 + bias[nb + 1];
        st.z = v2 + bias[nb + 2]; st.w = v3 + bias[nb + 3];
        *(float4*)((float*)Cout + (size_t)row * Nn + nb) = st;
      }
    }
  }
#undef STG
#undef RDA
#undef RDB
#undef MM
#undef WLG
#undef WVM8
#undef WVM4
#undef WVM0
#undef BAR
#undef PRIO1
#undef PRIO0
}

// ---------------- kv partials via MFMA (unchanged from R6) ----------------
__global__ __launch_bounds__(256) void kv_ksum_mfma(const u16* __restrict__ qkv,
                                                    float* __restrict__ kvpart,
                                                    float* __restrict__ kspart) {
  const int bh = blockIdx.x >> 3;
  const int chunk = blockIdx.x & 7;
  const int b = bh >> 4, h = bh & 15;
  __shared__ u16 kT[64 * 64];
  __shared__ u16 vT[80 * 64];
  const int tid  = threadIdx.x;
  const int lane = tid & 63;
  const int w    = tid >> 6;
  const int lrow = lane & 15;
  const int hi   = lane >> 4;

  for (int i = tid; i < 16 * 64; i += 256) {
    const int r = 64 + (i >> 6), n = i & 63;
    vT[r * 64 + (((n >> 3) ^ (r & 7)) << 3) + (n & 7)] = (r == 64) ? (u16)0x3F80 : (u16)0;
  }

  f32x4 acc[5] = {};
  const u16* kbase = qkv + (size_t)(b * SEQ) * NQKV + DIM     + h * DHEAD;
  const u16* vbase = qkv + (size_t)(b * SEQ) * NQKV + 2 * DIM + h * DHEAD;

  for (int r0 = chunk * 512; r0 < chunk * 512 + 512; r0 += 64) {
    __syncthreads();
    for (int s = tid; s < 512; s += 256) {
      const int r  = s >> 3;
      const int c0 = (s & 7) << 3;
      const s16x8 k8 = *(const s16x8*)(kbase + (size_t)(r0 + r) * NQKV + c0);
      const s16x8 v8 = *(const s16x8*)(vbase + (size_t)(r0 + r) * NQKV + c0);
      const int slot = r >> 3, nb = r & 7;
#pragma unroll
      for (int q = 0; q < 8; q++) {
        const int d = c0 + q;
        const int off = d * 64 + ((slot ^ (d & 7)) << 3) + nb;
        kT[off] = (u16)k8[q];
        vT[off] = (u16)v8[q];
      }
    }
    __syncthreads();
#pragma unroll
    for (int kk = 0; kk < 2; kk++) {
      const int drow = w * 16 + lrow;
      const s16x8 kf = *(const s16x8*)&kT[drow * 64 + (((kk * 4 + hi) ^ (drow & 7)) << 3)];
#pragma unroll
      for (int et = 0; et < 5; et++) {
        const int erow = et * 16 + lrow;
        const s16x8 vf = *(const s16x8*)&vT[erow * 64 + (((kk * 4 + hi) ^ (erow & 7)) << 3)];
        acc[et] = __builtin_amdgcn_mfma_f32_16x16x32_bf16(vf, kf, acc[et], 0, 0, 0);
      }
    }
  }

  const int d = w * 16 + lrow;
  float* outp = kvpart + (size_t)blockIdx.x * 4096;
#pragma unroll
  for (int et = 0; et < 4; et++)
    *(f32x4*)&outp[d * 64 + et * 16 + hi * 4] = acc[et];
  if (hi == 0) kspart[(size_t)blockIdx.x * 64 + d] = acc[4][0];
}

// ---------------- attn out via MFMA, self-reducing the 8 kv partials ----------------
// Staging iterates the LINEAR partial index l = d*64+e (coalesced 1KB/wave reads
// of the L2-hot 128KB partial block — fixes R13's 256B-stride scatter), summing
// c = 0..7 ascending (same order as the old reduce_kv -> bit-identical). Only
// the cheap LDS write scatters. Partials come from the previous dispatch on the
// same stream, so plain loads are safe.
__global__ __launch_bounds__(256) void attn_mfma(const u16* __restrict__ qkv,
                                                 const float* __restrict__ kvpart,
                                                 const float* __restrict__ kspart,
                                                 u16* __restrict__ attn) {
  const int bh = blockIdx.x >> 4;
  const int mc = blockIdx.x & 15;
  const int b = bh >> 4, h = bh & 15;
  __shared__ u16 BT[2][80][64];
  __shared__ float nrm[256];
  const int tid  = threadIdx.x;
  const int lane = tid & 63;
  const int w    = tid >> 6;
  const int lrow = lane & 15;
  const int hi   = lane >> 4;

  const float* pbase = kvpart + (size_t)(bh * 8) * 4096;
#pragma unroll
  for (int s = 0; s < 16; s++) {
    const int l = tid + 256 * s;        // l = d*64 + e  (coalesced)
    float v = 0.f;
#pragma unroll
    for (int c = 0; c < 8; c++) v += pbase[c * 4096 + l];
    const int d = l >> 6, e = l & 63;
    const u16 vh = f2bf(v);
    const u16 vl = f2bf(v - bf2f(vh));
    const int off = e * 64 + (((d >> 3) ^ (e & 7)) << 3) + (d & 7);
    BT[0][0][off] = vh;
    BT[1][0][off] = vl;
  }
  if (tid < 64) {                       // e == 64 row: k-sum; swz(d,e=64) = d
    float v = 0.f;
#pragma unroll
    for (int c = 0; c < 8; c++) v += kspart[bh * 8 * 64 + c * 64 + tid];
    const u16 vh = f2bf(v);
    const u16 vl = f2bf(v - bf2f(vh));
    BT[0][0][64 * 64 + tid] = vh;
    BT[1][0][64 * 64 + tid] = vl;
  }
  for (int i = tid; i < 15 * 64; i += 256) {   // e = 65..79: zeros
    const int e = 65 + (i >> 6), d = i & 63;
    const int off = e * 64 + (((d >> 3) ^ (e & 7)) << 3) + (d & 7);
    BT[0][0][off] = 0;
    BT[1][0][off] = 0;
  }

  const int rloc = w * 64 + lrow;
  const u16* qbase = qkv + (size_t)(b * SEQ + mc * 256 + rloc) * NQKV + h * DHEAD + hi * 8;
  s16x8 af[4][2];
#pragma unroll
  for (int mi = 0; mi < 4; mi++)
#pragma unroll
    for (int kk = 0; kk < 2; kk++)
      af[mi][kk] = *(const s16x8*)(qbase + (size_t)(mi * 16) * NQKV + kk * 32);

  __syncthreads();

  f32x4 acc[4][5] = {};
#pragma unroll
  for (int wv = 0; wv < 2; wv++) {
#pragma unroll
    for (int jb = 0; jb < 5; jb++) {
      const int erow = jb * 16 + lrow;
      const int sx = erow & 7;
      s16x8 bq0 = *(const s16x8*)&BT[wv][erow][((0 * 4 + hi) ^ sx) << 3];
      s16x8 bq1 = *(const s16x8*)&BT[wv][erow][((1 * 4 + hi) ^ sx) << 3];
#pragma unroll
      for (int mi = 0; mi < 4; mi++) {
        acc[mi][jb] = __builtin_amdgcn_mfma_f32_16x16x32_bf16(bq0, af[mi][0], acc[mi][jb], 0, 0, 0);
        acc[mi][jb] = __builtin_amdgcn_mfma_f32_16x16x32_bf16(bq1, af[mi][1], acc[mi][jb], 0, 0, 0);
      }
    }
  }

  if (hi == 0) {
#pragma unroll
    for (int mi = 0; mi < 4; mi++) nrm[rloc + mi * 16] = acc[mi][4][0] + 1e-6f;
  }
  __syncthreads();

  u16* obase = attn + (size_t)(b * SEQ + mc * 256 + rloc) * DIM + h * DHEAD + hi * 4;
#pragma unroll
  for (int mi = 0; mi < 4; mi++) {
    const float sc = 1.f / nrm[rloc + mi * 16];
#pragma unroll
    for (int jb = 0; jb < 4; jb++) {
      uint2 st;
      st.x = (uint32_t)f2bf(acc[mi][jb][0] * sc) | ((uint32_t)f2bf(acc[mi][jb][1] * sc) << 16);
      st.y = (uint32_t)f2bf(acc[mi][jb][2] * sc) | ((uint32_t)f2bf(acc[mi][jb][3] * sc) << 16);
      *(uint2*)(obase + (size_t)(mi * 16) * DIM + jb * 16) = st;
    }
  }
}

extern "C" void kernel_launch(void* const* d_in, const int* in_sizes, int n_in,
                              void* d_out, int out_size, void* d_ws, size_t ws_size,
                              hipStream_t stream) {
  (void)in_sizes; (void)n_in; (void)out_size; (void)ws_size;
  const float* x     = (const float*)d_in[0];
  const float* Wqkv  = (const float*)d_in[1];
  const float* Wf    = (const float*)d_in[2];
  const float* bfv   = (const float*)d_in[3];
  const float* Wout  = (const float*)d_in[4];
  const float* bout  = (const float*)d_in[5];
  float* out = (float*)d_out;
  char* ws = (char*)d_ws;

  u16*   wqkvT = (u16*)(ws + 0);              // 3072*1024 bf16   = 6,291,456 B
  u16*   woutT = (u16*)(ws + 6291456);        // 1024*1024 bf16   = 2,097,152 B
  u16*   xb    = (u16*)(ws + 8388608);        // 16384*1024 bf16  = 33,554,432 B
  u16*   qkvb  = (u16*)(ws + 41943040);       // 16384*3072 bf16  = 100,663,296 B
  u16*   attn  = (u16*)(ws + 142606336);      // 16384*1024 bf16  = 33,554,432 B
  float* kvp   = (float*)(ws + 176160768);    // 512*4096 f32     = 8,388,608 B
  float* ksp   = (float*)(ws + 184549376);    // 512*64 f32       = 131,072 B

  prep<<<2816, 256, 0, stream>>>(x, Wqkv, Wf, Wout, xb, wqkvT, woutT);
  gemm4p<1><<<(MROWS / 256) * (NQKV / 256), 512, 0, stream>>>(xb, wqkvT, qkvb, bfv,
                                                              NQKV, DIM);
  kv_ksum_mfma<<<64 * 8, 256, 0, stream>>>(qkvb, kvp, ksp);
  attn_mfma<<<64 * 16, 256, 0, stream>>>(qkvb, kvp, ksp, attn);
  gemm4p<2><<<(MROWS / 256) * (DIM / 256), 512, 0, stream>>>(attn, woutT, out, bout,
                                                             DIM, DIM);
}